// Round 1
// baseline (371.702 us; speedup 1.0000x reference)
//
#include <hip/hip_runtime.h>

typedef unsigned short ushort_t;
typedef unsigned int   uint_t;
typedef __attribute__((ext_vector_type(8))) short  short8;
typedef __attribute__((ext_vector_type(4))) float  float4v;
typedef __attribute__((ext_vector_type(4))) uint_t uint4v;

#define B_    16
#define CIN_  320
#define COUT_ 320
#define NLORA 50
#define R_    4

// workspace layout (bytes)
#define XPAD_ELEMS ((size_t)B_ * 66 * 66 * CIN_)   // bf16 NHWC padded x
#define WEFF_OFF   (XPAD_ELEMS * 2)                // 44,605,440 B (16B aligned)

__device__ __forceinline__ ushort_t bf16rne(float f) {
  uint_t u = __float_as_uint(f);
  u = (u + 0x7FFFu + ((u >> 16) & 1u)) >> 16;
  return (ushort_t)u;
}

// ---------------------------------------------------------------------------
// Kernel 1: x [B][C][H][W] fp32  ->  x_pad [B][66][66][C] bf16 (interior only;
// borders are pre-zeroed by memset). LDS transpose for coalescing both sides.
// ---------------------------------------------------------------------------
__global__ __launch_bounds__(256)
void pad_convert(const float* __restrict__ x, ushort_t* __restrict__ x_pad) {
  __shared__ float t[64][65];
  const int cc  = blockIdx.x;   // channel chunk 0..4 (64 ch each)
  const int h   = blockIdx.y;   // 0..63
  const int b   = blockIdx.z;
  const int tid = threadIdx.x;
  #pragma unroll
  for (int it = 0; it < 16; ++it) {
    int idx = it * 256 + tid;
    int cl = idx >> 6, wl = idx & 63;
    t[cl][wl] = x[(((size_t)(b * CIN_ + cc * 64 + cl)) * 64 + h) * 64 + wl];
  }
  __syncthreads();
  #pragma unroll
  for (int it = 0; it < 8; ++it) {
    int flat = (it * 256 + tid) * 2;          // even: (wl, cl-pair)
    int wl = flat >> 6, cl = flat & 63;
    uint_t u0 = bf16rne(t[cl][wl]);
    uint_t u1 = bf16rne(t[cl + 1][wl]);
    *(uint_t*)(x_pad + (((size_t)(b * 66 + h + 1)) * 66 + (wl + 1)) * CIN_ + cc * 64 + cl)
        = u0 | (u1 << 16);
  }
}

// ---------------------------------------------------------------------------
// Kernel 2: merged per-sample weights
//   W_eff[b][tap][o][c] = bf16( conv_w[o][c][tap] + act * sum_r up[l][o][r]*down[l][r][c][tap] )
// ---------------------------------------------------------------------------
__global__ __launch_bounds__(320)
void merge_weights(const float* __restrict__ conv_w, const float* __restrict__ down_w,
                   const float* __restrict__ up_w,  const void* __restrict__ lora,
                   ushort_t* __restrict__ W_eff) {
  const int o = blockIdx.x;       // 0..319
  const int b = blockIdx.y;       // 0..15
  const int c = threadIdx.x;      // 0..319

  // int32 vs int64 lora_id detection (reads only the first 64 B, valid either way)
  const int* p32 = (const int*)lora;
  bool odd0 = true;
  #pragma unroll
  for (int i = 1; i < 16; i += 2) odd0 = odd0 && (p32[i] == 0);
  long long raw = odd0 ? ((const long long*)lora)[b] : (long long)p32[b];
  long long idx = (raw >= 0) ? (raw >> 2) : -(((-raw) + 3) >> 2);   // floor(raw/4)
  float act = (idx >= 0) ? 1.0f : 0.0f;                              // SCALE==1.0 folded
  int l = (int)(idx < 0 ? 0 : (idx > (NLORA - 1) ? (NLORA - 1) : idx));

  float up[R_];
  #pragma unroll
  for (int r = 0; r < R_; ++r)
    up[r] = up_w[((size_t)l * COUT_ + o) * R_ + r] * act;

  #pragma unroll
  for (int tap = 0; tap < 9; ++tap) {
    float v = conv_w[((size_t)o * CIN_ + c) * 9 + tap];
    #pragma unroll
    for (int r = 0; r < R_; ++r)
      v += up[r] * down_w[(((size_t)l * R_ + r) * CIN_ + c) * 9 + tap];
    W_eff[(((size_t)b * 9 + tap) * COUT_ + o) * CIN_ + c] = bf16rne(v);
  }
}

// ---------------------------------------------------------------------------
// Kernel 3: main implicit-GEMM conv, bf16 MFMA 16x16x32, fp32 accumulate.
// Block: 256 thr (4 waves). Tile: M=256 (4 rows x 64 cols), N=64, K chunks of
// 32 channels x 9 taps. Wave w computes output row h0+w (4 m-subs x 4 n-subs).
// LDS: XOR-swizzled (chunk q ^= (inner&3)) -> conflict-free b128, no padding.
// ---------------------------------------------------------------------------
__global__ __launch_bounds__(256, 2)
void conv_main(const ushort_t* __restrict__ x_pad, const ushort_t* __restrict__ W_eff,
               const float* __restrict__ conv_b, float* __restrict__ out) {
  __shared__ char smem[62208];
  ushort_t* xs = (ushort_t*)smem;              // [6][66][32] bf16, swizzled
  ushort_t* wt = (ushort_t*)(smem + 25344);    // [9][64][32] bf16, swizzled

  const int tid = threadIdx.x;
  const int b   = blockIdx.z;
  const int h0  = blockIdx.x * 4;   // first output row of tile
  const int o0  = blockIdx.y * 64;  // first output channel of tile

  const int wv = tid >> 6;          // wave 0..3
  const int la = tid & 15;
  const int q  = (tid >> 4) & 3;    // k-quad within wave

  float4v acc[4][4];
  #pragma unroll
  for (int i = 0; i < 4; ++i)
    #pragma unroll
    for (int n = 0; n < 4; ++n) acc[i][n] = (float4v)0.0f;

  for (int c0 = 0; c0 < CIN_; c0 += 32) {
    __syncthreads();
    // stage x halo tile: padded rows h0..h0+5, cols 0..65, ch c0..c0+31
    for (int g = tid; g < 6 * 66 * 4; g += 256) {
      int qq = g & 3;
      int t  = g >> 2;
      int ww = t % 66;
      int hh = t / 66;
      const uint4v v = *(const uint4v*)(x_pad +
          (((size_t)(b * 66 + h0 + hh) * 66 + ww) * CIN_ + c0 + qq * 8));
      *(uint4v*)(xs + ((hh * 66 + ww) * 32 + ((qq ^ (ww & 3)) * 8))) = v;
    }
    // stage weight tile: taps 0..8, o0..o0+63, ch c0..c0+31
    for (int g = tid; g < 9 * 64 * 4; g += 256) {
      int qq  = g & 3;
      int o   = (g >> 2) & 63;
      int tap = g >> 8;
      const uint4v v = *(const uint4v*)(W_eff +
          (((size_t)(b * 9 + tap) * COUT_ + o0 + o) * CIN_ + c0 + qq * 8));
      *(uint4v*)(wt + ((tap * 64 + o) * 32 + ((qq ^ (o & 3)) * 8))) = v;
    }
    __syncthreads();

    #pragma unroll
    for (int tap = 0; tap < 9; ++tap) {
      const int kh = tap / 3, kw = tap % 3;
      short8 bf[4];
      #pragma unroll
      for (int n = 0; n < 4; ++n) {
        int o = n * 16 + la;
        bf[n] = *(const short8*)(wt + ((tap * 64 + o) * 32 + ((q ^ (o & 3)) * 8)));
      }
      const int hh = wv + kh;
      #pragma unroll
      for (int i = 0; i < 4; ++i) {
        int ww = i * 16 + la + kw;
        short8 af = *(const short8*)(xs + ((hh * 66 + ww) * 32 + ((q ^ (ww & 3)) * 8)));
        #pragma unroll
        for (int n = 0; n < 4; ++n)
          acc[i][n] = __builtin_amdgcn_mfma_f32_16x16x32_bf16(af, bf[n], acc[i][n], 0, 0, 0);
      }
    }
  }

  // Epilogue: transpose C through LDS (two 32-channel halves), add bias,
  // coalesced float4 NCHW stores.
  float* lc = (float*)smem;   // [32][260] fp32
  #pragma unroll
  for (int half = 0; half < 2; ++half) {
    __syncthreads();
    #pragma unroll
    for (int nn = 0; nn < 2; ++nn) {
      const int nsub  = half * 2 + nn;
      const int n_loc = nn * 16 + la;
      #pragma unroll
      for (int i = 0; i < 4; ++i) {
        const int m_base = (wv * 4 + i) * 16 + q * 4;  // 4 consecutive m per reg
        *(float4v*)(lc + n_loc * 260 + m_base) = acc[i][nsub];
      }
    }
    __syncthreads();
    for (int f = tid; f < 32 * 64; f += 256) {
      int n_loc = f >> 6;
      int m4 = (f & 63) * 4;
      int o = o0 + half * 32 + n_loc;
      float4v v = *(const float4v*)(lc + n_loc * 260 + m4);
      v += conv_b[o];
      *(float4v*)(out + ((size_t)(b * COUT_ + o) * 4096) + h0 * 64 + m4) = v;
    }
  }
}

// ---------------------------------------------------------------------------
extern "C" void kernel_launch(void* const* d_in, const int* in_sizes, int n_in,
                              void* d_out, int out_size, void* d_ws, size_t ws_size,
                              hipStream_t stream) {
  const float* x      = (const float*)d_in[0];
  const float* conv_w = (const float*)d_in[1];
  const float* conv_b = (const float*)d_in[2];
  const float* down_w = (const float*)d_in[3];
  const float* up_w   = (const float*)d_in[4];
  const void*  lora   = d_in[5];
  float* out = (float*)d_out;

  ushort_t* x_pad = (ushort_t*)d_ws;
  ushort_t* W_eff = (ushort_t*)((char*)d_ws + WEFF_OFF);

  // zero x_pad (borders must be 0; ws is re-poisoned before every launch)
  hipMemsetAsync(d_ws, 0, WEFF_OFF, stream);

  pad_convert  <<<dim3(5, 64, 16),  256, 0, stream>>>(x, x_pad);
  merge_weights<<<dim3(320, 16),    320, 0, stream>>>(conv_w, down_w, up_w, lora, W_eff);
  conv_main    <<<dim3(16, 5, 16),  256, 0, stream>>>(x_pad, W_eff, conv_b, out);
}